// Round 13
// baseline (703.175 us; speedup 1.0000x reference)
//
#include <hip/hip_runtime.h>
#include <hip/hip_bf16.h>

// LSTM: B=1024, T=512, I=4, H=128, O=4. Gate order i,f,g,o (PyTorch).
// out = h_T @ W_fc^T + b_fc
//
// ROUND 13: dual-tile software pipelining. Each block owns 32 batch rows =
// TWO independent 16-row recurrences (A,B) sharing the weight registers.
// Per iteration, two phases:
//   phase 1: MFMA gates_A(t)        || VALU: act(gates_B(t-1)) -> h_B(t) -> LDS
//   phase 2: MFMA gates_B(t)        || VALU: act(gates_A(t))   -> h_A(t+1) -> LDS
// The VALU work is INDEPENDENT of the in-flight MFMAs (other tile), so the
// matrix and VALU pipes overlap inside each wave: phase ~ max(M,V) instead of
// M+V (r7-r12 measured serial: 620+1080 of an 1742-cyc step). Grid 32 blocks.
// Single LDS buffer per tile (write and read separated by the phase barriers).
// Activation math identical to r12 (batched reciprocal, pre-scaled log2e).

#define Tlen 512
#define Iin  4
#define Hdim 128
#define Odim 4

#define SB0() __builtin_amdgcn_sched_barrier(0)

typedef __attribute__((ext_vector_type(8))) short bf16x8;
typedef __attribute__((ext_vector_type(4))) float f32x4;
typedef __attribute__((ext_vector_type(2))) unsigned uint2v;
typedef __attribute__((ext_vector_type(4))) unsigned uint4v;

static __device__ __forceinline__ short f2bf(float f) {
  union { float f; unsigned u; } v; v.f = f;
  unsigned u = v.u;
  return (short)((u + 0x7FFFu + ((u >> 16) & 1u)) >> 16);  // RNE
}
static __device__ __forceinline__ unsigned cvt_pk_bf16(float lo, float hi) {
  unsigned r;
  asm("v_cvt_pk_bf16_f32 %0, %1, %2" : "=v"(r) : "v"(lo), "v"(hi));
  return r;
}
static __device__ __forceinline__ float ex2(float x) { return __builtin_amdgcn_exp2f(x); }
static __device__ __forceinline__ float rcp_(float x) { return __builtin_amdgcn_rcpf(x); }

#define MFMA __builtin_amdgcn_mfma_f32_16x16x32_bf16

__global__ __launch_bounds__(512) void lstm_kernel(
    const float* __restrict__ x, const float* __restrict__ W_ih,
    const float* __restrict__ W_hh, const float* __restrict__ b_ih,
    const float* __restrict__ b_hh, const float* __restrict__ W_fc,
    const float* __restrict__ b_fc, float* __restrict__ out) {
  // one h buffer per tile (phase barriers separate write from read)
  __shared__ alignas(16) short bufA[16][168];
  __shared__ alignas(16) short bufB[16][168];
  __shared__ float hfin[32][Hdim];

  const int tid  = threadIdx.x;
  const int wid  = tid >> 6;    // wave 0..7 -> hidden cols wid*16..+15
  const int lane = tid & 63;
  const int m16  = lane & 15;   // batch row within tile / weight row
  const int grp  = lane >> 4;   // k-group 0..3
  const int bbase = blockIdx.x * 32;   // 32 rows per block (two tiles)
  const float L2E = 1.4426950408889634f;

  // ---- weight fragments (A-operand), pre-scaled, shared by both tiles ----
  bf16x8 Wf[4][4];
  bf16x8 Wx[4];
  f32x4  c0v[4];
#pragma unroll
  for (int q = 0; q < 4; ++q) {
    const float sc = (q == 2) ? 2.0f * L2E : L2E;   // g-gate: tanh needs 2x
    const int gm = q * 128 + wid * 16 + m16;
#pragma unroll
    for (int kc = 0; kc < 4; ++kc) {
      const float* src = W_hh + (size_t)gm * Hdim + kc * 32 + grp * 8;
      bf16x8 w;
#pragma unroll
      for (int e = 0; e < 8; ++e) w[e] = f2bf(src[e] * sc);
      Wf[q][kc] = w;
    }
    bf16x8 w4 = {0, 0, 0, 0, 0, 0, 0, 0};
    if (grp == 0) {
#pragma unroll
      for (int e = 0; e < 4; ++e) w4[e] = f2bf(W_ih[gm * Iin + e] * sc);
    }
    Wx[q] = w4;
#pragma unroll
    for (int r = 0; r < 4; ++r) {
      const int gr = q * 128 + wid * 16 + grp * 4 + r;
      c0v[q][r] = (b_ih[gr] + b_hh[gr]) * sc;
    }
  }

  // ---- zero h buffers (h(0) = 0) ----
  for (int i = tid; i < 16 * 168; i += 512) {
    ((short*)bufA)[i] = 0;
    ((short*)bufB)[i] = 0;
  }

  const float* xrowA = x + (size_t)(bbase + m16) * (Tlen * Iin);
  const float* xrowB = xrowA + (size_t)16 * (Tlen * Iin);

  // ---- acc init: bias + Wx @ x(0) for both tiles ----
  f32x4 accA0, accA1, accA2, accA3, accB0, accB1, accB2, accB3;
  {
    f32x4 xa = *(const f32x4*)xrowA;
    uint4v u;
    u[0] = cvt_pk_bf16(xa[0], xa[1]);
    u[1] = cvt_pk_bf16(xa[2], xa[3]);
    u[2] = 0; u[3] = 0;
    union { uint4v uu; bf16x8 v; } cst; cst.uu = u;
    accA0 = MFMA(Wx[0], cst.v, c0v[0], 0, 0, 0);
    accA1 = MFMA(Wx[1], cst.v, c0v[1], 0, 0, 0);
    accA2 = MFMA(Wx[2], cst.v, c0v[2], 0, 0, 0);
    accA3 = MFMA(Wx[3], cst.v, c0v[3], 0, 0, 0);
  }
  {
    f32x4 xb = *(const f32x4*)xrowB;
    uint4v u;
    u[0] = cvt_pk_bf16(xb[0], xb[1]);
    u[1] = cvt_pk_bf16(xb[2], xb[3]);
    u[2] = 0; u[3] = 0;
    union { uint4v uu; bf16x8 v; } cst; cst.uu = u;
    accB0 = MFMA(Wx[0], cst.v, c0v[0], 0, 0, 0);
    accB1 = MFMA(Wx[1], cst.v, c0v[1], 0, 0, 0);
    accB2 = MFMA(Wx[2], cst.v, c0v[2], 0, 0, 0);
    accB3 = MFMA(Wx[3], cst.v, c0v[3], 0, 0, 0);
  }

  float c4A[4] = {0.f, 0.f, 0.f, 0.f};
  float c4B[4] = {0.f, 0.f, 0.f, 0.f};
  float hlA[4] = {0.f, 0.f, 0.f, 0.f};
  float hlB[4] = {0.f, 0.f, 0.f, 0.f};
  __syncthreads();

  // ---- peeled phase 1 of iter 0: MFMA A only (h_A(0)=0) ----
  {
    bf16x8 a0 = *(const bf16x8*)&bufA[m16][ 0 + grp * 8];
    bf16x8 a1 = *(const bf16x8*)&bufA[m16][32 + grp * 8];
    bf16x8 a2 = *(const bf16x8*)&bufA[m16][64 + grp * 8];
    bf16x8 a3 = *(const bf16x8*)&bufA[m16][96 + grp * 8];
    accA0 = MFMA(Wf[0][0], a0, accA0, 0, 0, 0);
    accA1 = MFMA(Wf[1][0], a0, accA1, 0, 0, 0);
    accA2 = MFMA(Wf[2][0], a0, accA2, 0, 0, 0);
    accA3 = MFMA(Wf[3][0], a0, accA3, 0, 0, 0);
    accA0 = MFMA(Wf[0][1], a1, accA0, 0, 0, 0);
    accA1 = MFMA(Wf[1][1], a1, accA1, 0, 0, 0);
    accA2 = MFMA(Wf[2][1], a1, accA2, 0, 0, 0);
    accA3 = MFMA(Wf[3][1], a1, accA3, 0, 0, 0);
    accA0 = MFMA(Wf[0][2], a2, accA0, 0, 0, 0);
    accA1 = MFMA(Wf[1][2], a2, accA1, 0, 0, 0);
    accA2 = MFMA(Wf[2][2], a2, accA2, 0, 0, 0);
    accA3 = MFMA(Wf[3][2], a2, accA3, 0, 0, 0);
    accA0 = MFMA(Wf[0][3], a3, accA0, 0, 0, 0);
    accA1 = MFMA(Wf[1][3], a3, accA1, 0, 0, 0);
    accA2 = MFMA(Wf[2][3], a3, accA2, 0, 0, 0);
    accA3 = MFMA(Wf[3][3], a3, accA3, 0, 0, 0);
  }
  __syncthreads();

  for (int t = 0; t < Tlen; ++t) {
    // ================= PHASE 2 (iter t): MFMA B(t)  ||  VALU A =================
    {
      bf16x8 v0 = *(const bf16x8*)&bufB[m16][ 0 + grp * 8];
      bf16x8 v1 = *(const bf16x8*)&bufB[m16][32 + grp * 8];
      bf16x8 v2 = *(const bf16x8*)&bufB[m16][64 + grp * 8];
      bf16x8 v3 = *(const bf16x8*)&bufB[m16][96 + grp * 8];
      const int tnA = (t + 1 < Tlen) ? (t + 1) : (Tlen - 1);
      f32x4 xvA = *(const f32x4*)(xrowA + (size_t)tnA * Iin);

      accB0 = MFMA(Wf[0][0], v0, accB0, 0, 0, 0);
      accB1 = MFMA(Wf[1][0], v0, accB1, 0, 0, 0);
      accB2 = MFMA(Wf[2][0], v0, accB2, 0, 0, 0);
      accB3 = MFMA(Wf[3][0], v0, accB3, 0, 0, 0);
      SB0();
      // V_A chunk 1: p-values for sigma_i, sigma_f
      float Ai0 = 1.0f + ex2(-accA0[0]), Ai1 = 1.0f + ex2(-accA0[1]);
      float Ai2 = 1.0f + ex2(-accA0[2]), Ai3 = 1.0f + ex2(-accA0[3]);
      float Af0 = 1.0f + ex2(-accA1[0]), Af1 = 1.0f + ex2(-accA1[1]);
      float Af2 = 1.0f + ex2(-accA1[2]), Af3 = 1.0f + ex2(-accA1[3]);
      SB0();
      accB0 = MFMA(Wf[0][1], v1, accB0, 0, 0, 0);
      accB1 = MFMA(Wf[1][1], v1, accB1, 0, 0, 0);
      accB2 = MFMA(Wf[2][1], v1, accB2, 0, 0, 0);
      accB3 = MFMA(Wf[3][1], v1, accB3, 0, 0, 0);
      SB0();
      // V_A chunk 2: finish si, sf (batched rcp)
      f32x4 si, sf;
      {
        float r01 = rcp_(Ai0 * Ai1), r23 = rcp_(Ai2 * Ai3);
        si[0] = r01 * Ai1; si[1] = r01 * Ai0; si[2] = r23 * Ai3; si[3] = r23 * Ai2;
        float q01 = rcp_(Af0 * Af1), q23 = rcp_(Af2 * Af3);
        sf[0] = q01 * Af1; sf[1] = q01 * Af0; sf[2] = q23 * Af3; sf[3] = q23 * Af2;
      }
      SB0();
      accB0 = MFMA(Wf[0][2], v2, accB0, 0, 0, 0);
      accB1 = MFMA(Wf[1][2], v2, accB1, 0, 0, 0);
      accB2 = MFMA(Wf[2][2], v2, accB2, 0, 0, 0);
      accB3 = MFMA(Wf[3][2], v2, accB3, 0, 0, 0);
      SB0();
      // V_A chunk 3: gt (tanh) and so
      f32x4 gt, so;
      {
        float p0 = 1.0f + ex2(-accA2[0]), p1 = 1.0f + ex2(-accA2[1]);
        float p2 = 1.0f + ex2(-accA2[2]), p3 = 1.0f + ex2(-accA2[3]);
        float r01 = rcp_(p0 * p1), r23 = rcp_(p2 * p3);
        float r01_2 = r01 + r01, r23_2 = r23 + r23;
        gt[0] = __builtin_fmaf(r01_2, p1, -1.0f);
        gt[1] = __builtin_fmaf(r01_2, p0, -1.0f);
        gt[2] = __builtin_fmaf(r23_2, p3, -1.0f);
        gt[3] = __builtin_fmaf(r23_2, p2, -1.0f);
        float s0 = 1.0f + ex2(-accA3[0]), s1 = 1.0f + ex2(-accA3[1]);
        float s2 = 1.0f + ex2(-accA3[2]), s3 = 1.0f + ex2(-accA3[3]);
        float u01 = rcp_(s0 * s1), u23 = rcp_(s2 * s3);
        so[0] = u01 * s1; so[1] = u01 * s0; so[2] = u23 * s3; so[3] = u23 * s2;
      }
      SB0();
      accB0 = MFMA(Wf[0][3], v3, accB0, 0, 0, 0);
      accB1 = MFMA(Wf[1][3], v3, accB1, 0, 0, 0);
      accB2 = MFMA(Wf[2][3], v3, accB2, 0, 0, 0);
      accB3 = MFMA(Wf[3][3], v3, accB3, 0, 0, 0);
      SB0();
      // V_A chunk 4: cell, cell-tanh, h, pack, LDS write, acc reinit
#pragma unroll
      for (int r = 0; r < 4; ++r)
        c4A[r] = __builtin_fmaf(sf[r], c4A[r], si[r] * gt[r]);
      {
        float p0 = 1.0f + ex2(-2.8853900817779268f * c4A[0]);
        float p1 = 1.0f + ex2(-2.8853900817779268f * c4A[1]);
        float p2 = 1.0f + ex2(-2.8853900817779268f * c4A[2]);
        float p3 = 1.0f + ex2(-2.8853900817779268f * c4A[3]);
        float r01 = rcp_(p0 * p1), r23 = rcp_(p2 * p3);
        float r01_2 = r01 + r01, r23_2 = r23 + r23;
        hlA[0] = so[0] * __builtin_fmaf(r01_2, p1, -1.0f);
        hlA[1] = so[1] * __builtin_fmaf(r01_2, p0, -1.0f);
        hlA[2] = so[2] * __builtin_fmaf(r23_2, p3, -1.0f);
        hlA[3] = so[3] * __builtin_fmaf(r23_2, p2, -1.0f);
      }
      uint2v hp;
      hp[0] = cvt_pk_bf16(hlA[0], hlA[1]);
      hp[1] = cvt_pk_bf16(hlA[2], hlA[3]);
      *(uint2v*)&bufA[m16][wid * 16 + grp * 4] = hp;
      {
        uint4v u;
        u[0] = cvt_pk_bf16(xvA[0], xvA[1]);
        u[1] = cvt_pk_bf16(xvA[2], xvA[3]);
        u[2] = 0; u[3] = 0;
        union { uint4v uu; bf16x8 v; } cst; cst.uu = u;
        accA0 = MFMA(Wx[0], cst.v, c0v[0], 0, 0, 0);
        accA1 = MFMA(Wx[1], cst.v, c0v[1], 0, 0, 0);
        accA2 = MFMA(Wx[2], cst.v, c0v[2], 0, 0, 0);
        accA3 = MFMA(Wx[3], cst.v, c0v[3], 0, 0, 0);
      }
    }
    __syncthreads();

    // ============ PHASE 1 (iter t+1): MFMA A(t+1)  ||  VALU B ============
    if (t + 1 < Tlen) {
      const int tt = t + 1;  // B consumes gates_B(tt-1) -> h_B(tt)
      bf16x8 a0 = *(const bf16x8*)&bufA[m16][ 0 + grp * 8];
      bf16x8 a1 = *(const bf16x8*)&bufA[m16][32 + grp * 8];
      bf16x8 a2 = *(const bf16x8*)&bufA[m16][64 + grp * 8];
      bf16x8 a3 = *(const bf16x8*)&bufA[m16][96 + grp * 8];
      f32x4 xvB = *(const f32x4*)(xrowB + (size_t)tt * Iin);

      accA0 = MFMA(Wf[0][0], a0, accA0, 0, 0, 0);
      accA1 = MFMA(Wf[1][0], a0, accA1, 0, 0, 0);
      accA2 = MFMA(Wf[2][0], a0, accA2, 0, 0, 0);
      accA3 = MFMA(Wf[3][0], a0, accA3, 0, 0, 0);
      SB0();
      float Bi0 = 1.0f + ex2(-accB0[0]), Bi1 = 1.0f + ex2(-accB0[1]);
      float Bi2 = 1.0f + ex2(-accB0[2]), Bi3 = 1.0f + ex2(-accB0[3]);
      float Bf0 = 1.0f + ex2(-accB1[0]), Bf1 = 1.0f + ex2(-accB1[1]);
      float Bf2 = 1.0f + ex2(-accB1[2]), Bf3 = 1.0f + ex2(-accB1[3]);
      SB0();
      accA0 = MFMA(Wf[0][1], a1, accA0, 0, 0, 0);
      accA1 = MFMA(Wf[1][1], a1, accA1, 0, 0, 0);
      accA2 = MFMA(Wf[2][1], a1, accA2, 0, 0, 0);
      accA3 = MFMA(Wf[3][1], a1, accA3, 0, 0, 0);
      SB0();
      f32x4 si, sf;
      {
        float r01 = rcp_(Bi0 * Bi1), r23 = rcp_(Bi2 * Bi3);
        si[0] = r01 * Bi1; si[1] = r01 * Bi0; si[2] = r23 * Bi3; si[3] = r23 * Bi2;
        float q01 = rcp_(Bf0 * Bf1), q23 = rcp_(Bf2 * Bf3);
        sf[0] = q01 * Bf1; sf[1] = q01 * Bf0; sf[2] = q23 * Bf3; sf[3] = q23 * Bf2;
      }
      SB0();
      accA0 = MFMA(Wf[0][2], a2, accA0, 0, 0, 0);
      accA1 = MFMA(Wf[1][2], a2, accA1, 0, 0, 0);
      accA2 = MFMA(Wf[2][2], a2, accA2, 0, 0, 0);
      accA3 = MFMA(Wf[3][2], a2, accA3, 0, 0, 0);
      SB0();
      f32x4 gt, so;
      {
        float p0 = 1.0f + ex2(-accB2[0]), p1 = 1.0f + ex2(-accB2[1]);
        float p2 = 1.0f + ex2(-accB2[2]), p3 = 1.0f + ex2(-accB2[3]);
        float r01 = rcp_(p0 * p1), r23 = rcp_(p2 * p3);
        float r01_2 = r01 + r01, r23_2 = r23 + r23;
        gt[0] = __builtin_fmaf(r01_2, p1, -1.0f);
        gt[1] = __builtin_fmaf(r01_2, p0, -1.0f);
        gt[2] = __builtin_fmaf(r23_2, p3, -1.0f);
        gt[3] = __builtin_fmaf(r23_2, p2, -1.0f);
        float s0 = 1.0f + ex2(-accB3[0]), s1 = 1.0f + ex2(-accB3[1]);
        float s2 = 1.0f + ex2(-accB3[2]), s3 = 1.0f + ex2(-accB3[3]);
        float u01 = rcp_(s0 * s1), u23 = rcp_(s2 * s3);
        so[0] = u01 * s1; so[1] = u01 * s0; so[2] = u23 * s3; so[3] = u23 * s2;
      }
      SB0();
      accA0 = MFMA(Wf[0][3], a3, accA0, 0, 0, 0);
      accA1 = MFMA(Wf[1][3], a3, accA1, 0, 0, 0);
      accA2 = MFMA(Wf[2][3], a3, accA2, 0, 0, 0);
      accA3 = MFMA(Wf[3][3], a3, accA3, 0, 0, 0);
      SB0();
#pragma unroll
      for (int r = 0; r < 4; ++r)
        c4B[r] = __builtin_fmaf(sf[r], c4B[r], si[r] * gt[r]);
      {
        float p0 = 1.0f + ex2(-2.8853900817779268f * c4B[0]);
        float p1 = 1.0f + ex2(-2.8853900817779268f * c4B[1]);
        float p2 = 1.0f + ex2(-2.8853900817779268f * c4B[2]);
        float p3 = 1.0f + ex2(-2.8853900817779268f * c4B[3]);
        float r01 = rcp_(p0 * p1), r23 = rcp_(p2 * p3);
        float r01_2 = r01 + r01, r23_2 = r23 + r23;
        hlB[0] = so[0] * __builtin_fmaf(r01_2, p1, -1.0f);
        hlB[1] = so[1] * __builtin_fmaf(r01_2, p0, -1.0f);
        hlB[2] = so[2] * __builtin_fmaf(r23_2, p3, -1.0f);
        hlB[3] = so[3] * __builtin_fmaf(r23_2, p2, -1.0f);
      }
      uint2v hp;
      hp[0] = cvt_pk_bf16(hlB[0], hlB[1]);
      hp[1] = cvt_pk_bf16(hlB[2], hlB[3]);
      *(uint2v*)&bufB[m16][wid * 16 + grp * 4] = hp;
      {
        uint4v u;
        u[0] = cvt_pk_bf16(xvB[0], xvB[1]);
        u[1] = cvt_pk_bf16(xvB[2], xvB[3]);
        u[2] = 0; u[3] = 0;
        union { uint4v uu; bf16x8 v; } cst; cst.uu = u;
        accB0 = MFMA(Wx[0], cst.v, c0v[0], 0, 0, 0);
        accB1 = MFMA(Wx[1], cst.v, c0v[1], 0, 0, 0);
        accB2 = MFMA(Wx[2], cst.v, c0v[2], 0, 0, 0);
        accB3 = MFMA(Wx[3], cst.v, c0v[3], 0, 0, 0);
      }
      __syncthreads();
    }
  }

  // ---- epilogue: finish tile B's last step (gates_B(511) -> h_B(512)) ----
  {
    f32x4 si, sf, gt, so;
    {
      float p0 = 1.0f + ex2(-accB0[0]), p1 = 1.0f + ex2(-accB0[1]);
      float p2 = 1.0f + ex2(-accB0[2]), p3 = 1.0f + ex2(-accB0[3]);
      float r01 = rcp_(p0 * p1), r23 = rcp_(p2 * p3);
      si[0] = r01 * p1; si[1] = r01 * p0; si[2] = r23 * p3; si[3] = r23 * p2;
    }
    {
      float p0 = 1.0f + ex2(-accB1[0]), p1 = 1.0f + ex2(-accB1[1]);
      float p2 = 1.0f + ex2(-accB1[2]), p3 = 1.0f + ex2(-accB1[3]);
      float r01 = rcp_(p0 * p1), r23 = rcp_(p2 * p3);
      sf[0] = r01 * p1; sf[1] = r01 * p0; sf[2] = r23 * p3; sf[3] = r23 * p2;
    }
    {
      float p0 = 1.0f + ex2(-accB2[0]), p1 = 1.0f + ex2(-accB2[1]);
      float p2 = 1.0f + ex2(-accB2[2]), p3 = 1.0f + ex2(-accB2[3]);
      float r01 = rcp_(p0 * p1), r23 = rcp_(p2 * p3);
      float r01_2 = r01 + r01, r23_2 = r23 + r23;
      gt[0] = __builtin_fmaf(r01_2, p1, -1.0f);
      gt[1] = __builtin_fmaf(r01_2, p0, -1.0f);
      gt[2] = __builtin_fmaf(r23_2, p3, -1.0f);
      gt[3] = __builtin_fmaf(r23_2, p2, -1.0f);
    }
    {
      float p0 = 1.0f + ex2(-accB3[0]), p1 = 1.0f + ex2(-accB3[1]);
      float p2 = 1.0f + ex2(-accB3[2]), p3 = 1.0f + ex2(-accB3[3]);
      float r01 = rcp_(p0 * p1), r23 = rcp_(p2 * p3);
      so[0] = r01 * p1; so[1] = r01 * p0; so[2] = r23 * p3; so[3] = r23 * p2;
    }
#pragma unroll
    for (int r = 0; r < 4; ++r)
      c4B[r] = __builtin_fmaf(sf[r], c4B[r], si[r] * gt[r]);
    {
      float p0 = 1.0f + ex2(-2.8853900817779268f * c4B[0]);
      float p1 = 1.0f + ex2(-2.8853900817779268f * c4B[1]);
      float p2 = 1.0f + ex2(-2.8853900817779268f * c4B[2]);
      float p3 = 1.0f + ex2(-2.8853900817779268f * c4B[3]);
      float r01 = rcp_(p0 * p1), r23 = rcp_(p2 * p3);
      float r01_2 = r01 + r01, r23_2 = r23 + r23;
      hlB[0] = so[0] * __builtin_fmaf(r01_2, p1, -1.0f);
      hlB[1] = so[1] * __builtin_fmaf(r01_2, p0, -1.0f);
      hlB[2] = so[2] * __builtin_fmaf(r23_2, p3, -1.0f);
      hlB[3] = so[3] * __builtin_fmaf(r23_2, p2, -1.0f);
    }
  }

  // ---- final FC: out = h_T @ W_fc^T + b_fc (32 rows) ----
  {
    f32x4 hv;
    hv[0] = hlA[0]; hv[1] = hlA[1]; hv[2] = hlA[2]; hv[3] = hlA[3];
    *(f32x4*)&hfin[m16][wid * 16 + grp * 4] = hv;
    f32x4 hw;
    hw[0] = hlB[0]; hw[1] = hlB[1]; hw[2] = hlB[2]; hw[3] = hlB[3];
    *(f32x4*)&hfin[16 + m16][wid * 16 + grp * 4] = hw;
  }
  __syncthreads();
  if (tid < 128) {
    const int row = tid >> 2, o = tid & 3;
    float s = b_fc[o];
#pragma unroll 8
    for (int k = 0; k < Hdim; ++k) s += hfin[row][k] * W_fc[o * Hdim + k];
    out[(size_t)(bbase + row) * Odim + o] = s;
  }
}

extern "C" void kernel_launch(void* const* d_in, const int* in_sizes, int n_in,
                              void* d_out, int out_size, void* d_ws, size_t ws_size,
                              hipStream_t stream) {
  const float* x    = (const float*)d_in[0];
  const float* W_ih = (const float*)d_in[1];
  const float* W_hh = (const float*)d_in[2];
  const float* b_ih = (const float*)d_in[3];
  const float* b_hh = (const float*)d_in[4];
  const float* W_fc = (const float*)d_in[5];
  const float* b_fc = (const float*)d_in[6];
  float* out = (float*)d_out;
  lstm_kernel<<<32, 512, 0, stream>>>(x, W_ih, W_hh, b_ih, b_hh, W_fc, b_fc, out);
}

// Round 17
// 357.104 us; speedup vs baseline: 1.9691x; 1.9691x over previous
//
#include <hip/hip_runtime.h>
#include <hip/hip_bf16.h>

// LSTM: B=1024, T=512, I=4, H=128, O=4. Gate order i,f,g,o (PyTorch).
// out = h_T @ W_fc^T + b_fc
//
// 64 blocks x 16 batch rows, full T-loop on-chip; per step gates = W@[h|x]^T
// via mfma_f32_16x16x32_bf16, x-projection folded into acc init (register
// MFMAs at end of previous step). Thread owns 4 consecutive hidden cols of
// one batch row for all gates -> in-register c/h update. Batched reciprocal
// (1 v_rcp per 2 sigmoids). SB0-pinned chain/activation weave (r12, +2%).
//
// ROUND 17 (= r14/r15/r16 resubmit; all died on infra before the source
// reached the container): r13 dual-tile measured the overlap tradeoff:
// V > M means any multi-tile-per-CU scheme walls at k*V > M+V -- family
// closed. r12's additive model validated to 0.1% (512 x (620+1080+45)/2.4GHz
// = 372us). This round isolates V's non-algorithmic overhead: #pragma
// unroll 2 (compile-time cur/nxt, halved loop control; pragma form passed in
// r6) and tn = (t+1) & 511 instead of clamp (wraps to in-bounds dup-load of
// x(0) whose acc is never consumed). Identical arithmetic otherwise.
// Null result => V is trans-pipe floor => ROOFLINE next round.

#define Tlen 512
#define Iin  4
#define Hdim 128
#define Odim 4

#define SB0() __builtin_amdgcn_sched_barrier(0)

typedef __attribute__((ext_vector_type(8))) short bf16x8;
typedef __attribute__((ext_vector_type(4))) float f32x4;
typedef __attribute__((ext_vector_type(2))) unsigned uint2v;
typedef __attribute__((ext_vector_type(4))) unsigned uint4v;

static __device__ __forceinline__ short f2bf(float f) {
  union { float f; unsigned u; } v; v.f = f;
  unsigned u = v.u;
  return (short)((u + 0x7FFFu + ((u >> 16) & 1u)) >> 16);  // RNE
}
static __device__ __forceinline__ unsigned cvt_pk_bf16(float lo, float hi) {
  unsigned r;
  asm("v_cvt_pk_bf16_f32 %0, %1, %2" : "=v"(r) : "v"(lo), "v"(hi));
  return r;
}
static __device__ __forceinline__ float ex2(float x) { return __builtin_amdgcn_exp2f(x); }
static __device__ __forceinline__ float rcp_(float x) { return __builtin_amdgcn_rcpf(x); }

#define MFMA __builtin_amdgcn_mfma_f32_16x16x32_bf16

__global__ __launch_bounds__(512) void lstm_kernel(
    const float* __restrict__ x, const float* __restrict__ W_ih,
    const float* __restrict__ W_hh, const float* __restrict__ b_ih,
    const float* __restrict__ b_hh, const float* __restrict__ W_fc,
    const float* __restrict__ b_fc, float* __restrict__ out) {
  // h double-buffer: [buf][batch row][k]; row stride 168 shorts = 336 B.
  __shared__ alignas(16) short Albuf[2][16][168];
  __shared__ float hfin[16][Hdim];

  const int tid  = threadIdx.x;
  const int wid  = tid >> 6;    // wave 0..7 -> hidden cols wid*16..+15
  const int lane = tid & 63;
  const int m16  = lane & 15;   // batch row / weight row within tile
  const int grp  = lane >> 4;   // k-group 0..3
  const int bbase = blockIdx.x * 16;
  const float L2E = 1.4426950408889634f;

  // ---- weight fragments (A-operand), pre-scaled, registers for whole kernel ----
  bf16x8 Wf[4][4];
  bf16x8 Wx[4];
  f32x4  c0v[4];
#pragma unroll
  for (int q = 0; q < 4; ++q) {
    const float sc = (q == 2) ? 2.0f * L2E : L2E;   // g-gate: tanh needs 2x
    const int gm = q * 128 + wid * 16 + m16;        // weight row this lane holds
#pragma unroll
    for (int kc = 0; kc < 4; ++kc) {
      const float* src = W_hh + (size_t)gm * Hdim + kc * 32 + grp * 8;
      bf16x8 w;
#pragma unroll
      for (int e = 0; e < 8; ++e) w[e] = f2bf(src[e] * sc);
      Wf[q][kc] = w;
    }
    bf16x8 w4 = {0, 0, 0, 0, 0, 0, 0, 0};  // x-chunk A: [W_ih(4)|0...] at k=0..3
    if (grp == 0) {
#pragma unroll
      for (int e = 0; e < 4; ++e) w4[e] = f2bf(W_ih[gm * Iin + e] * sc);
    }
    Wx[q] = w4;
#pragma unroll
    for (int r = 0; r < 4; ++r) {
      const int gr = q * 128 + wid * 16 + grp * 4 + r;  // this thread's gate col
      c0v[q][r] = (b_ih[gr] + b_hh[gr]) * sc;
    }
  }

  // ---- zero h buffers ----
  for (int i = tid; i < 2 * 16 * 168; i += 512) ((short*)Albuf)[i] = 0;

  const float* xrow = x + (size_t)(bbase + m16) * (Tlen * Iin);

  // ---- acc = bias + Wx @ x(0) (register-only MFMAs) ----
  f32x4 acc0, acc1, acc2, acc3;
  {
    f32x4 xv = *(const f32x4*)xrow;
    uint4v u;
    u[0] = cvt_pk_bf16(xv[0], xv[1]);
    u[1] = cvt_pk_bf16(xv[2], xv[3]);
    u[2] = 0; u[3] = 0;
    union { uint4v uu; bf16x8 v; } cst; cst.uu = u;
    acc0 = MFMA(Wx[0], cst.v, c0v[0], 0, 0, 0);
    acc1 = MFMA(Wx[1], cst.v, c0v[1], 0, 0, 0);
    acc2 = MFMA(Wx[2], cst.v, c0v[2], 0, 0, 0);
    acc3 = MFMA(Wx[3], cst.v, c0v[3], 0, 0, 0);
  }

  float c4[4] = {0.f, 0.f, 0.f, 0.f};
  float hl[4] = {0.f, 0.f, 0.f, 0.f};
  __syncthreads();

#pragma unroll 2
  for (int t = 0; t < Tlen; ++t) {
    const int cur = t & 1, nxt = cur ^ 1;

    // B fragments of h(t); x(t+1) prefetch (t=511 wraps to x(0): in-bounds
    // dup-load whose acc re-init is never consumed)
    bf16x8 b0 = *(const bf16x8*)&Albuf[cur][m16][ 0 + grp * 8];
    bf16x8 b1 = *(const bf16x8*)&Albuf[cur][m16][32 + grp * 8];
    bf16x8 b2 = *(const bf16x8*)&Albuf[cur][m16][64 + grp * 8];
    bf16x8 b3 = *(const bf16x8*)&Albuf[cur][m16][96 + grp * 8];
    const int tn = (t + 1) & (Tlen - 1);
    f32x4 xv = *(const f32x4*)(xrow + (size_t)tn * Iin);

    // ---- software-pipelined chains: q0,q1 | si | q2 | sf | q3 | gt | so ----
    acc0 = MFMA(Wf[0][0], b0, acc0, 0, 0, 0);
    acc0 = MFMA(Wf[0][1], b1, acc0, 0, 0, 0);
    acc0 = MFMA(Wf[0][2], b2, acc0, 0, 0, 0);
    acc0 = MFMA(Wf[0][3], b3, acc0, 0, 0, 0);
    acc1 = MFMA(Wf[1][0], b0, acc1, 0, 0, 0);
    acc1 = MFMA(Wf[1][1], b1, acc1, 0, 0, 0);
    acc1 = MFMA(Wf[1][2], b2, acc1, 0, 0, 0);
    acc1 = MFMA(Wf[1][3], b3, acc1, 0, 0, 0);
    SB0();
    f32x4 si;
    {
      float p0 = 1.0f + ex2(-acc0[0]), p1 = 1.0f + ex2(-acc0[1]);
      float p2 = 1.0f + ex2(-acc0[2]), p3 = 1.0f + ex2(-acc0[3]);
      float r01 = rcp_(p0 * p1), r23 = rcp_(p2 * p3);
      si[0] = r01 * p1; si[1] = r01 * p0; si[2] = r23 * p3; si[3] = r23 * p2;
    }
    SB0();
    acc2 = MFMA(Wf[2][0], b0, acc2, 0, 0, 0);
    acc2 = MFMA(Wf[2][1], b1, acc2, 0, 0, 0);
    acc2 = MFMA(Wf[2][2], b2, acc2, 0, 0, 0);
    acc2 = MFMA(Wf[2][3], b3, acc2, 0, 0, 0);
    SB0();
    f32x4 sf;
    {
      float p0 = 1.0f + ex2(-acc1[0]), p1 = 1.0f + ex2(-acc1[1]);
      float p2 = 1.0f + ex2(-acc1[2]), p3 = 1.0f + ex2(-acc1[3]);
      float r01 = rcp_(p0 * p1), r23 = rcp_(p2 * p3);
      sf[0] = r01 * p1; sf[1] = r01 * p0; sf[2] = r23 * p3; sf[3] = r23 * p2;
    }
    SB0();
    acc3 = MFMA(Wf[3][0], b0, acc3, 0, 0, 0);
    acc3 = MFMA(Wf[3][1], b1, acc3, 0, 0, 0);
    acc3 = MFMA(Wf[3][2], b2, acc3, 0, 0, 0);
    acc3 = MFMA(Wf[3][3], b3, acc3, 0, 0, 0);
    SB0();
    f32x4 gt;
    {
      float p0 = 1.0f + ex2(-acc2[0]), p1 = 1.0f + ex2(-acc2[1]);
      float p2 = 1.0f + ex2(-acc2[2]), p3 = 1.0f + ex2(-acc2[3]);
      float r01 = rcp_(p0 * p1), r23 = rcp_(p2 * p3);
      float r01_2 = r01 + r01, r23_2 = r23 + r23;
      gt[0] = __builtin_fmaf(r01_2, p1, -1.0f);
      gt[1] = __builtin_fmaf(r01_2, p0, -1.0f);
      gt[2] = __builtin_fmaf(r23_2, p3, -1.0f);
      gt[3] = __builtin_fmaf(r23_2, p2, -1.0f);
    }
    SB0();
    f32x4 so;
    {
      float p0 = 1.0f + ex2(-acc3[0]), p1 = 1.0f + ex2(-acc3[1]);
      float p2 = 1.0f + ex2(-acc3[2]), p3 = 1.0f + ex2(-acc3[3]);
      float r01 = rcp_(p0 * p1), r23 = rcp_(p2 * p3);
      so[0] = r01 * p1; so[1] = r01 * p0; so[2] = r23 * p3; so[3] = r23 * p2;
    }

    // cell update + paired cell-tanh
#pragma unroll
    for (int r = 0; r < 4; ++r)
      c4[r] = __builtin_fmaf(sf[r], c4[r], si[r] * gt[r]);
    {
      float p0 = 1.0f + ex2(-2.8853900817779268f * c4[0]);
      float p1 = 1.0f + ex2(-2.8853900817779268f * c4[1]);
      float p2 = 1.0f + ex2(-2.8853900817779268f * c4[2]);
      float p3 = 1.0f + ex2(-2.8853900817779268f * c4[3]);
      float r01 = rcp_(p0 * p1), r23 = rcp_(p2 * p3);
      float r01_2 = r01 + r01, r23_2 = r23 + r23;
      hl[0] = so[0] * __builtin_fmaf(r01_2, p1, -1.0f);
      hl[1] = so[1] * __builtin_fmaf(r01_2, p0, -1.0f);
      hl[2] = so[2] * __builtin_fmaf(r23_2, p3, -1.0f);
      hl[3] = so[3] * __builtin_fmaf(r23_2, p2, -1.0f);
    }

    // pack h(t+1): one ds_write_b64
    uint2v hp;
    hp[0] = cvt_pk_bf16(hl[0], hl[1]);
    hp[1] = cvt_pk_bf16(hl[2], hl[3]);
    *(uint2v*)&Albuf[nxt][m16][wid * 16 + grp * 4] = hp;

    // re-init acc = bias + Wx @ x(t+1) (register-only; drains during barrier)
    {
      uint4v u;
      u[0] = cvt_pk_bf16(xv[0], xv[1]);
      u[1] = cvt_pk_bf16(xv[2], xv[3]);
      u[2] = 0; u[3] = 0;
      union { uint4v uu; bf16x8 v; } cst; cst.uu = u;
      acc0 = MFMA(Wx[0], cst.v, c0v[0], 0, 0, 0);
      acc1 = MFMA(Wx[1], cst.v, c0v[1], 0, 0, 0);
      acc2 = MFMA(Wx[2], cst.v, c0v[2], 0, 0, 0);
      acc3 = MFMA(Wx[3], cst.v, c0v[3], 0, 0, 0);
    }

    __syncthreads();
  }

  // ---- final FC: out = h_T @ W_fc^T + b_fc ----
  {
    f32x4 hv;
    hv[0] = hl[0]; hv[1] = hl[1]; hv[2] = hl[2]; hv[3] = hl[3];
    *(f32x4*)&hfin[m16][wid * 16 + grp * 4] = hv;
  }
  __syncthreads();
  if (tid < 64) {
    const int row = tid >> 2, o = tid & 3;
    float s = b_fc[o];
#pragma unroll 8
    for (int k = 0; k < Hdim; ++k) s += hfin[row][k] * W_fc[o * Hdim + k];
    out[(size_t)(bbase + row) * Odim + o] = s;
  }
}

extern "C" void kernel_launch(void* const* d_in, const int* in_sizes, int n_in,
                              void* d_out, int out_size, void* d_ws, size_t ws_size,
                              hipStream_t stream) {
  const float* x    = (const float*)d_in[0];
  const float* W_ih = (const float*)d_in[1];
  const float* W_hh = (const float*)d_in[2];
  const float* b_ih = (const float*)d_in[3];
  const float* b_hh = (const float*)d_in[4];
  const float* W_fc = (const float*)d_in[5];
  const float* b_fc = (const float*)d_in[6];
  float* out = (float*)d_out;
  lstm_kernel<<<64, 512, 0, stream>>>(x, W_ih, W_hh, b_ih, b_hh, W_fc, b_fc, out);
}